// Round 5
// baseline (343.258 us; speedup 1.0000x reference)
//
#include <hip/hip_runtime.h>
#include <math.h>
#include <stdint.h>

#define D_MODEL 1024
#define NHEADS  16
#define DK      64
#define BATCH   4
#define SEQ     2048
#define MROWS   (BATCH * SEQ)              // 8192
#define TENS    ((size_t)MROWS * D_MODEL)  // 8.39M elems
#define WELT    ((size_t)D_MODEL * D_MODEL)

typedef __attribute__((ext_vector_type(8))) _Float16 f16x8;
typedef __attribute__((ext_vector_type(4))) _Float16 f16x4;
typedef __attribute__((ext_vector_type(2))) __fp16 h16x2;
typedef __attribute__((ext_vector_type(4))) float f32x4;
typedef __attribute__((ext_vector_type(8))) unsigned short us8;
typedef __attribute__((ext_vector_type(4))) unsigned short us4;

__device__ __forceinline__ unsigned short f2h(float x) {
    _Float16 h = (_Float16)x;
    return __builtin_bit_cast(unsigned short, h);
}

#if __has_builtin(__builtin_amdgcn_exp2f)
__device__ __forceinline__ float fexp2(float x) { return __builtin_amdgcn_exp2f(x); }
#else
__device__ __forceinline__ float fexp2(float x) { return exp2f(x); }
#endif

// k=16 f16 MFMA (legacy shape, still native on gfx950): lane layouts
// A: row=l&15, k=(l>>4)*4+e ; B: col=l&15, k=(l>>4)*4+e ; C: col=l&15, row=(l>>4)*4+r
__device__ __forceinline__ f32x4 mfma16(f16x4 a, f16x4 b, f32x4 c) {
#if __has_builtin(__builtin_amdgcn_mfma_f32_16x16x16f16)
    return __builtin_amdgcn_mfma_f32_16x16x16f16(a, b, c, 0, 0, 0);
#else
    asm("v_mfma_f32_16x16x16_f16 %0, %1, %2, %0" : "+v"(c) : "v"(a), "v"(b));
    return c;
#endif
}

// async global->LDS, 16B per lane; LDS dst is wave-uniform base + lane*16
__device__ __forceinline__ void gld_lds16(const void* g, void* l) {
    __builtin_amdgcn_global_load_lds(
        (__attribute__((address_space(1))) void*)(uintptr_t)(g),
        (__attribute__((address_space(3))) void*)(unsigned)(uintptr_t)(l),
        16, 0, 0);
}

// ---------------------------------------------------------------------------
// fp32 -> f16 conversion of all inputs into workspace.
// seg 0..2: Q/K/V tensors (TENS each). seg 3: all four weight matrices.
// ---------------------------------------------------------------------------
__global__ __launch_bounds__(256)
void convert_kernel(const float* __restrict__ q, const float* __restrict__ k,
                    const float* __restrict__ v, const float* __restrict__ wq,
                    const float* __restrict__ wk, const float* __restrict__ wv,
                    const float* __restrict__ wo, unsigned short* __restrict__ dst)
{
    const int seg = blockIdx.y;
    size_t i = ((size_t)blockIdx.x * 256 + threadIdx.x) * 4;
    const float* src;
    size_t doff, soff;
    if (seg < 3) {
        if (i >= TENS) return;
        src = (seg == 0) ? q : (seg == 1) ? k : v;
        soff = i;
        doff = (size_t)seg * TENS + i;
    } else {
        if (i >= 4 * WELT) return;
        const int widx = (int)(i >> 20);          // WELT == 1<<20
        src = (widx == 0) ? wq : (widx == 1) ? wk : (widx == 2) ? wv : wo;
        soff = i & (WELT - 1);
        doff = 3 * TENS + i;
    }
    float4 f = *(const float4*)(src + soff);
    us4 o = { f2h(f.x), f2h(f.y), f2h(f.z), f2h(f.w) };
    *(us4*)(dst + doff) = o;
}

// ---------------------------------------------------------------------------
// f16 MFMA NT GEMM: C[M,N] = A[M,K] @ B[N,K]^T
// 128x128 tile, 256 thr = 4 waves, BK=64.
// 2-deep LDS pipeline (64 KB -> 2 blocks/CU for barrier-stall overlap):
// counted s_waitcnt vmcnt(8) in steady state (tile t's 8 loads are the
// oldest of 16 outstanding); next-next tile staged right after barrier2
// so its latency hides under the NEXT tile's compute AND the co-resident
// block's work. Raw s_barrier (no implicit full drain).
// omode: 0 = fp32 row-major, 1 = f16 row-major,
//        2 = f16 V-transpose, granule-interleaved [b][h][s/8][d][s%8]
// ---------------------------------------------------------------------------
__device__ __forceinline__
void gemm_body(const unsigned short* __restrict__ A,
               const unsigned short* __restrict__ B,
               void* __restrict__ C, int N, int K, int omode,
               unsigned short* As, unsigned short* Bs)
{
    const int tid  = threadIdx.x;
    const int wave = tid >> 6;
    const int lane = tid & 63;
    const int g    = lane >> 4;
    const int m15  = lane & 15;
    const int bm   = blockIdx.x * 128;
    const int bn   = blockIdx.y * 128;

    const int srw = lane >> 3;
    const int lc  = (lane & 7) ^ srw;

    const int wr = (wave >> 1) * 64;
    const int wc = (wave & 1) * 64;

    f32x4 acc[4][4];
#pragma unroll
    for (int i = 0; i < 4; ++i)
#pragma unroll
        for (int j = 0; j < 4; ++j) acc[i][j] = (f32x4){0.f, 0.f, 0.f, 0.f};

    // 8 gld_lds per wave per call -- the vmcnt accounting unit.
    auto stage = [&](int buf, int t) {
        const int k0 = t * 64;
#pragma unroll
        for (int i = 0; i < 4; ++i) {
            const int rb = wave * 32 + i * 8;
            gld_lds16(A + (size_t)(bm + rb + srw) * K + k0 + lc * 8,
                      &As[buf * (128 * 64) + rb * 64]);
            gld_lds16(B + (size_t)(bn + rb + srw) * K + k0 + lc * 8,
                      &Bs[buf * (128 * 64) + rb * 64]);
        }
    };

    auto compute = [&](int buf) {
        const unsigned short* Ab = &As[buf * (128 * 64)];
        const unsigned short* Bb = &Bs[buf * (128 * 64)];
#pragma unroll
        for (int t = 0; t < 2; ++t) {
            f16x8 af[4], bf[4];
#pragma unroll
            for (int i = 0; i < 4; ++i) {
                int row = wr + i * 16 + m15;
                int pc  = (4 * t + g) ^ (row & 7);
                af[i] = *(const f16x8*)&Ab[row * 64 + pc * 8];
            }
#pragma unroll
            for (int j = 0; j < 4; ++j) {
                int row = wc + j * 16 + m15;
                int pc  = (4 * t + g) ^ (row & 7);
                bf[j] = *(const f16x8*)&Bb[row * 64 + pc * 8];
            }
            __builtin_amdgcn_s_setprio(1);
#pragma unroll
            for (int i = 0; i < 4; ++i)
#pragma unroll
                for (int j = 0; j < 4; ++j)
                    acc[i][j] = __builtin_amdgcn_mfma_f32_16x16x32_f16(
                        af[i], bf[j], acc[i][j], 0, 0, 0);
            __builtin_amdgcn_s_setprio(0);
        }
    };

    const int NT = K / 64;   // 16
    stage(0, 0);
    stage(1, 1);
    int cur = 0;
    for (int t = 0; t < NT; ++t) {
        if (t + 1 < NT) {
            // oldest 8 of <=16 outstanding are tile t's -> resident after this
            asm volatile("s_waitcnt vmcnt(8)" ::: "memory");
        } else {
            asm volatile("s_waitcnt vmcnt(0)" ::: "memory");
        }
        __builtin_amdgcn_s_barrier();            // tile t in LDS for all waves
        __builtin_amdgcn_sched_barrier(0);       // no ds_read hoists above barrier
        compute(cur);
        __builtin_amdgcn_sched_barrier(0);       // no ds_read sinks below barrier
        __builtin_amdgcn_s_barrier();            // all waves done reading buf cur
        if (t + 2 < NT) stage(cur, t + 2);       // overwrite freed buffer
        cur ^= 1;
    }

#pragma unroll
    for (int i = 0; i < 4; ++i) {
        const int gm0 = bm + wr + i * 16 + g * 4;
#pragma unroll
        for (int j = 0; j < 4; ++j) {
            const int gn = bn + wc + j * 16 + m15;
            if (omode == 0) {
#pragma unroll
                for (int r = 0; r < 4; ++r)
                    ((float*)C)[(size_t)(gm0 + r) * N + gn] = acc[i][j][r];
            } else if (omode == 1) {
#pragma unroll
                for (int r = 0; r < 4; ++r)
                    ((unsigned short*)C)[(size_t)(gm0 + r) * N + gn] = f2h(acc[i][j][r]);
            } else {
                const int b_ = gm0 >> 11, s_ = gm0 & 2047;
                const int h_ = gn >> 6,  d_ = gn & 63;
                us4 o = { f2h(acc[i][j][0]), f2h(acc[i][j][1]),
                          f2h(acc[i][j][2]), f2h(acc[i][j][3]) };
                // [b][h][s>>3][d][s&7]; s_&7 in {0,4} so the us4 is 8B-aligned
                *(us4*)((unsigned short*)C +
                        (((size_t)(b_ * NHEADS + h_) * 256 + (s_ >> 3)) * 64 + d_) * 8
                        + (s_ & 7)) = o;
            }
        }
    }
}

// Fused Q/K/V projections in one dispatch: blockIdx.z selects the GEMM.
__global__ __launch_bounds__(256, 2)
void proj3_kernel(const unsigned short* __restrict__ qb,
                  const unsigned short* __restrict__ kb,
                  const unsigned short* __restrict__ vb,
                  const unsigned short* __restrict__ wq,
                  const unsigned short* __restrict__ wk,
                  const unsigned short* __restrict__ wv,
                  unsigned short* __restrict__ qproj,
                  unsigned short* __restrict__ kproj,
                  unsigned short* __restrict__ vtw)
{
    __shared__ unsigned short As[2 * 128 * 64];   // 32 KB
    __shared__ unsigned short Bs[2 * 128 * 64];   // 32 KB
    const int z = blockIdx.z;
    const unsigned short* A = (z == 0) ? qb : (z == 1) ? kb : vb;
    const unsigned short* B = (z == 0) ? wq : (z == 1) ? wk : wv;
    void* C = (z == 0) ? (void*)qproj : (z == 1) ? (void*)kproj : (void*)vtw;
    gemm_body(A, B, C, D_MODEL, D_MODEL, (z == 2) ? 2 : 1, As, Bs);
}

__global__ __launch_bounds__(256, 2)
void gemm_out_kernel(const unsigned short* __restrict__ A,
                     const unsigned short* __restrict__ B,
                     float* __restrict__ C)
{
    __shared__ unsigned short As[2 * 128 * 64];
    __shared__ unsigned short Bs[2 * 128 * 64];
    gemm_body(A, B, C, D_MODEL, D_MODEL, 0, As, Bs);
}

// ---------------------------------------------------------------------------
// Flash attention, transposed-score form, 64 q/wave (mi=4), 2-phase pipeline.
// Grid (SEQ/256, NHEADS, BATCH), 256 thr = 4 waves; wave w owns 64 q-rows.
// K-tile = 64 keys, double-buffered (prefetch before compute, one barrier).
// S^T = K·Q^T (k=32 MFMA, log2-domain pre-scale); register online softmax.
// PV and denominator use k=16 MFMAs whose B-operand layout (col=m15,
// k=g*4+e) EXACTLY matches ST's register layout (key=km*16+g*4+r, q=m15):
// P^T never touches LDS -- no round-trip, no bank conflicts, no lgkm waits.
// qp,kp: [B,S,D_MODEL] f16; vt: [B,H,S/8,DK,8] f16 (granule-interleaved);
// ao: [B,S,D_MODEL] f16
// ---------------------------------------------------------------------------
__global__ __launch_bounds__(256, 2)
void attn_kernel(const unsigned short* __restrict__ qp,
                 const unsigned short* __restrict__ kp,
                 const unsigned short* __restrict__ vt,
                 unsigned short* __restrict__ ao)
{
    __shared__ unsigned short Ks[2][64 * 64];   // [buf][key][d], XOR-swizzled
    __shared__ unsigned short VTs[2][64 * 64];  // [buf][d][key], XOR-swizzled

    const int tid = threadIdx.x;
    const int w = tid >> 6, lane = tid & 63;
    const int g = lane >> 4, m15 = lane & 15;
    const int qt = blockIdx.x, h = blockIdx.y, b = blockIdx.z;

    const int q0 = qt * 256 + w * 64;
    const size_t rowbase = (size_t)b * SEQ;

    const int srw = lane >> 3;
    const int lc  = (lane & 7) ^ srw;

    // Q fragments (B-operand), pre-scaled by (1/sqrt(dk)) * log2(e)
    const _Float16 qscale = (_Float16)(0.125f * 1.4426950408889634f);
    f16x8 qf[4][2];
#pragma unroll
    for (int mi = 0; mi < 4; ++mi)
#pragma unroll
        for (int t = 0; t < 2; ++t) {
            f16x8 v = *(const f16x8*)(qp + (rowbase + q0 + mi * 16 + m15) * D_MODEL
                                      + h * DK + t * 32 + g * 8);
            qf[mi][t] = v * qscale;
        }

    const _Float16 one16 = (_Float16)1.f;
    const f16x4 ones4 = { one16, one16, one16, one16 };

    float mrun[4] = {-INFINITY, -INFINITY, -INFINITY, -INFINITY};
    float lrun[4] = {0.f, 0.f, 0.f, 0.f};

    f32x4 accO[4][4];
#pragma unroll
    for (int mi = 0; mi < 4; ++mi)
#pragma unroll
        for (int i = 0; i < 4; ++i) accO[mi][i] = (f32x4){0.f, 0.f, 0.f, 0.f};

    const unsigned short* kbase = kp + rowbase * D_MODEL + h * DK;
    const unsigned short* vbase = vt + (size_t)(b * NHEADS + h) * DK * SEQ;

    auto stage = [&](int buf, int t) {
#pragma unroll
        for (int it = 0; it < 2; ++it) {
            const int rb = w * 16 + it * 8;
            gld_lds16(kbase + (size_t)(t * 64 + rb + srw) * D_MODEL + lc * 8,
                      &Ks[buf][rb * 64]);
            // vt granule layout: elem = (s8*64 + d)*8 + (s&7); 16B = 8 s for one d
            gld_lds16(vbase + ((size_t)(t * 8 + lc) * 64 + rb + srw) * 8,
                      &VTs[buf][rb * 64]);
        }
    };

    const int NT = SEQ / 64;
    stage(0, 0);
    __syncthreads();   // compiler-emitted vmcnt(0) drains prologue loads

    for (int kt = 0; kt < NT; ++kt) {
        const int cur = kt & 1;
        if (kt + 1 < NT) stage(cur ^ 1, kt + 1);   // prefetch overlaps compute below

        // S^T (log2 domain): ST[km][mi] reg r: key=km*16+g*4+r, q=mi*16+m15
        f32x4 ST[4][4];
        __builtin_amdgcn_s_setprio(1);
#pragma unroll
        for (int km = 0; km < 4; ++km) {
            const int row = km * 16 + m15;
            f16x8 kf0 = *(const f16x8*)&Ks[cur][row * 64 + ((0 + g) ^ (row & 7)) * 8];
            f16x8 kf1 = *(const f16x8*)&Ks[cur][row * 64 + ((4 + g) ^ (row & 7)) * 8];
#pragma unroll
            for (int mi = 0; mi < 4; ++mi) {
                f32x4 z = (f32x4){0.f, 0.f, 0.f, 0.f};
                z = __builtin_amdgcn_mfma_f32_16x16x32_f16(kf0, qf[mi][0], z, 0, 0, 0);
                z = __builtin_amdgcn_mfma_f32_16x16x32_f16(kf1, qf[mi][1], z, 0, 0, 0);
                ST[km][mi] = z;
            }
        }
        __builtin_amdgcn_s_setprio(0);

        // register-resident online softmax in log2 domain (q = mi*16+m15);
        // P^T stays in registers as k16 B-operand fragments pb[mi][km].
        float scl[4];
        f16x4 pb[4][4];
#pragma unroll
        for (int mi = 0; mi < 4; ++mi) {
            float t0 = fmaxf(fmaxf(ST[0][mi][0], ST[0][mi][1]), ST[0][mi][2]);
            float t1 = fmaxf(fmaxf(ST[0][mi][3], ST[1][mi][0]), ST[1][mi][1]);
            float t2 = fmaxf(fmaxf(ST[1][mi][2], ST[1][mi][3]), ST[2][mi][0]);
            float t3 = fmaxf(fmaxf(ST[2][mi][1], ST[2][mi][2]), ST[2][mi][3]);
            float t4 = fmaxf(fmaxf(ST[3][mi][0], ST[3][mi][1]), ST[3][mi][2]);
            float u0 = fmaxf(fmaxf(t0, t1), t2);
            float u1 = fmaxf(fmaxf(t3, t4), ST[3][mi][3]);
            float mx = fmaxf(u0, u1);
            mx = fmaxf(mx, __shfl_xor(mx, 16));
            mx = fmaxf(mx, __shfl_xor(mx, 32));
            float mnew = fmaxf(mrun[mi], mx);
            scl[mi] = fexp2(mrun[mi] - mnew);
            mrun[mi] = mnew;
#pragma unroll
            for (int km = 0; km < 4; ++km) {
                float p0 = fexp2(ST[km][mi][0] - mnew);
                float p1 = fexp2(ST[km][mi][1] - mnew);
                float p2 = fexp2(ST[km][mi][2] - mnew);
                float p3 = fexp2(ST[km][mi][3] - mnew);
                h16x2 d0 = __builtin_amdgcn_cvt_pkrtz(p0, p1);
                h16x2 d1 = __builtin_amdgcn_cvt_pkrtz(p2, p3);
                uint2 wv = { __builtin_bit_cast(unsigned, d0),
                             __builtin_bit_cast(unsigned, d1) };
                pb[mi][km] = __builtin_bit_cast(f16x4, wv);
            }
            // denominator on the matrix pipe: zs col=q rows all = sum_k P^T[k][q]
            f32x4 zs = (f32x4){0.f, 0.f, 0.f, 0.f};
#pragma unroll
            for (int km = 0; km < 4; ++km) zs = mfma16(ones4, pb[mi][km], zs);
            lrun[mi] = lrun[mi] * scl[mi] + zs[0];
        }

        // wave-uniform skip of accO rescale when max didn't move anywhere
        int chg = (scl[0] < 1.f) | (scl[1] < 1.f) | (scl[2] < 1.f) | (scl[3] < 1.f);
        if (__any(chg)) {
#pragma unroll
            for (int mi = 0; mi < 4; ++mi)
#pragma unroll
                for (int i = 0; i < 4; ++i) accO[mi][i] *= scl[mi];
        }

        // O^T += V^T·P^T via k=16 MFMAs; A-frag = 8B conflict-free VTs reads
        __builtin_amdgcn_s_setprio(1);
#pragma unroll
        for (int i = 0; i < 4; ++i) {
            const int row = i * 16 + m15;
            f16x4 vf[4];
#pragma unroll
            for (int km = 0; km < 4; ++km) {
                // key = km*16 + g*4 + e: chunk = km*2 + (g>>1), half = g&1
                const int pc = (km * 2 + (g >> 1)) ^ (row & 7);
                vf[km] = *(const f16x4*)&VTs[cur][row * 64 + pc * 8 + (g & 1) * 4];
            }
#pragma unroll
            for (int mi = 0; mi < 4; ++mi) {
                f32x4 a = accO[mi][i];
#pragma unroll
                for (int km = 0; km < 4; ++km) a = mfma16(vf[km], pb[mi][km], a);
                accO[mi][i] = a;
            }
        }
        __builtin_amdgcn_s_setprio(0);

        __syncthreads();   // drains vmcnt(0) (prefetch done) + protects buffer reuse
    }

    // epilogue: O^T row d=i*16+g*4+r, col q=mi*16+m15 -> ao[b][s][h*64+d]
#pragma unroll
    for (int mi = 0; mi < 4; ++mi) {
        const float li = 1.f / lrun[mi];
        const size_t qg = rowbase + q0 + mi * 16 + m15;
#pragma unroll
        for (int i = 0; i < 4; ++i) {
            us4 o = { f2h(accO[mi][i][0] * li), f2h(accO[mi][i][1] * li),
                      f2h(accO[mi][i][2] * li), f2h(accO[mi][i][3] * li) };
            *(us4*)(ao + qg * D_MODEL + h * DK + i * 16 + g * 4) = o;
        }
    }
}

// ---------------------------------------------------------------------------
extern "C" void kernel_launch(void* const* d_in, const int* in_sizes, int n_in,
                              void* d_out, int out_size, void* d_ws, size_t ws_size,
                              hipStream_t stream)
{
    const float* Q  = (const float*)d_in[0];
    const float* K  = (const float*)d_in[1];
    const float* V  = (const float*)d_in[2];
    const float* Wq = (const float*)d_in[3];
    const float* Wk = (const float*)d_in[4];
    const float* Wv = (const float*)d_in[5];
    const float* Wo = (const float*)d_in[6];

    unsigned short* base = (unsigned short*)d_ws;
    unsigned short* qb = base;
    unsigned short* kb = qb + TENS;
    unsigned short* vb = kb + TENS;
    unsigned short* wq = vb + TENS;
    unsigned short* wk = wq + WELT;
    unsigned short* wv = wk + WELT;
    unsigned short* wo = wv + WELT;
    unsigned short* qproj = wo + WELT;
    unsigned short* kproj = qproj + TENS;
    unsigned short* vtw   = kproj + TENS;    // [B,H,S/8,DK,8] granule-interleaved
    unsigned short* aow   = vtw + TENS;

    convert_kernel<<<dim3(TENS / 1024, 4), 256, 0, stream>>>(Q, K, V, Wq, Wk, Wv, Wo, base);

    proj3_kernel<<<dim3(MROWS / 128, D_MODEL / 128, 3), 256, 0, stream>>>(
        qb, kb, vb, wq, wk, wv, qproj, kproj, vtw);

    attn_kernel<<<dim3(SEQ / 256, NHEADS, BATCH), 256, 0, stream>>>(
        qproj, kproj, vtw, aow);

    gemm_out_kernel<<<dim3(MROWS / 128, D_MODEL / 128), 256, 0, stream>>>(
        aow, wo, (float*)d_out);
}

// Round 6
// 320.599 us; speedup vs baseline: 1.0707x; 1.0707x over previous
//
#include <hip/hip_runtime.h>
#include <math.h>
#include <stdint.h>

#define D_MODEL 1024
#define NHEADS  16
#define DK      64
#define BATCH   4
#define SEQ     2048
#define MROWS   (BATCH * SEQ)              // 8192
#define TENS    ((size_t)MROWS * D_MODEL)  // 8.39M elems
#define WELT    ((size_t)D_MODEL * D_MODEL)

typedef __attribute__((ext_vector_type(8))) _Float16 f16x8;
typedef __attribute__((ext_vector_type(2))) __fp16 h16x2;
typedef __attribute__((ext_vector_type(4))) float f32x4;
typedef __attribute__((ext_vector_type(8))) unsigned short us8;
typedef __attribute__((ext_vector_type(4))) unsigned short us4;

__device__ __forceinline__ unsigned short f2h(float x) {
    _Float16 h = (_Float16)x;
    return __builtin_bit_cast(unsigned short, h);
}

#if __has_builtin(__builtin_amdgcn_exp2f)
__device__ __forceinline__ float fexp2(float x) { return __builtin_amdgcn_exp2f(x); }
#else
__device__ __forceinline__ float fexp2(float x) { return exp2f(x); }
#endif

// async global->LDS, 16B per lane; LDS dst is wave-uniform base + lane*16
__device__ __forceinline__ void gld_lds16(const void* g, void* l) {
    __builtin_amdgcn_global_load_lds(
        (__attribute__((address_space(1))) void*)(uintptr_t)(g),
        (__attribute__((address_space(3))) void*)(unsigned)(uintptr_t)(l),
        16, 0, 0);
}

// ---------------------------------------------------------------------------
// fp32 -> f16 conversion of all inputs into workspace.
// seg 0..2: Q/K/V tensors (TENS each). seg 3: all four weight matrices.
// ---------------------------------------------------------------------------
__global__ __launch_bounds__(256)
void convert_kernel(const float* __restrict__ q, const float* __restrict__ k,
                    const float* __restrict__ v, const float* __restrict__ wq,
                    const float* __restrict__ wk, const float* __restrict__ wv,
                    const float* __restrict__ wo, unsigned short* __restrict__ dst)
{
    const int seg = blockIdx.y;
    size_t i = ((size_t)blockIdx.x * 256 + threadIdx.x) * 4;
    const float* src;
    size_t doff, soff;
    if (seg < 3) {
        if (i >= TENS) return;
        src = (seg == 0) ? q : (seg == 1) ? k : v;
        soff = i;
        doff = (size_t)seg * TENS + i;
    } else {
        if (i >= 4 * WELT) return;
        const int widx = (int)(i >> 20);          // WELT == 1<<20
        src = (widx == 0) ? wq : (widx == 1) ? wk : (widx == 2) ? wv : wo;
        soff = i & (WELT - 1);
        doff = 3 * TENS + i;
    }
    float4 f = *(const float4*)(src + soff);
    us4 o = { f2h(f.x), f2h(f.y), f2h(f.z), f2h(f.w) };
    *(us4*)(dst + doff) = o;
}

// ---------------------------------------------------------------------------
// f16 MFMA NT GEMM: C[M,N] = A[M,K] @ B[N,K]^T
// 256x128 tile, 512 thr = 8 waves (4 row x 2 col, 64x64 each), BK=64.
// 3-deep LDS pipeline (144 KB): global_load_lds staged 2 tiles ahead,
// raw s_barrier with COUNTED s_waitcnt vmcnt(12/6/0) (T3+T4).
// bm/bn passed in: caller decodes an XCD-panel-grouped flat blockIdx (T1)
// so the 8 N-tiles sharing an A-panel run on ONE XCD -> A re-reads hit L2
// instead of HBM (A-panel re-fetch was ~8x = the dominant GEMM cost).
// omode: 0 = fp32 row-major, 1 = f16 row-major,
//        2 = f16 V-transpose, granule-interleaved [b][h][s/8][d][s%8]
// ---------------------------------------------------------------------------
__device__ __forceinline__
void gemm_body8(const unsigned short* __restrict__ A,
                const unsigned short* __restrict__ B,
                void* __restrict__ C, int N, int K, int omode,
                int bm, int bn,
                unsigned short* As, unsigned short* Bs)
{
    const int tid  = threadIdx.x;
    const int wave = tid >> 6;
    const int lane = tid & 63;
    const int g    = lane >> 4;
    const int m15  = lane & 15;

    const int srw = lane >> 3;
    const int lc  = (lane & 7) ^ srw;

    const int wr = (wave >> 1) * 64;   // 4 row-waves
    const int wc = (wave & 1) * 64;    // 2 col-waves

    f32x4 acc[4][4];
#pragma unroll
    for (int i = 0; i < 4; ++i)
#pragma unroll
        for (int j = 0; j < 4; ++j) acc[i][j] = (f32x4){0.f, 0.f, 0.f, 0.f};

    // 6 gld_lds per wave per call (4 A-rounds + 2 B-rounds) -- vmcnt unit.
    auto stage = [&](int buf, int t) {
        const int k0 = t * 64;
#pragma unroll
        for (int i = 0; i < 4; ++i) {
            const int rb = i * 64 + wave * 8;
            gld_lds16(A + (size_t)(bm + rb + srw) * K + k0 + lc * 8,
                      &As[buf * (256 * 64) + rb * 64]);
        }
#pragma unroll
        for (int j = 0; j < 2; ++j) {
            const int rb = j * 64 + wave * 8;
            gld_lds16(B + (size_t)(bn + rb + srw) * K + k0 + lc * 8,
                      &Bs[buf * (128 * 64) + rb * 64]);
        }
    };

    auto compute = [&](int buf) {
        const unsigned short* Ab = &As[buf * (256 * 64)];
        const unsigned short* Bb = &Bs[buf * (128 * 64)];
#pragma unroll
        for (int t = 0; t < 2; ++t) {
            f16x8 af[4], bf[4];
#pragma unroll
            for (int i = 0; i < 4; ++i) {
                int row = wr + i * 16 + m15;
                int pc  = (4 * t + g) ^ (row & 7);
                af[i] = *(const f16x8*)&Ab[row * 64 + pc * 8];
            }
#pragma unroll
            for (int j = 0; j < 4; ++j) {
                int row = wc + j * 16 + m15;
                int pc  = (4 * t + g) ^ (row & 7);
                bf[j] = *(const f16x8*)&Bb[row * 64 + pc * 8];
            }
            __builtin_amdgcn_s_setprio(1);
#pragma unroll
            for (int i = 0; i < 4; ++i)
#pragma unroll
                for (int j = 0; j < 4; ++j)
                    acc[i][j] = __builtin_amdgcn_mfma_f32_16x16x32_f16(
                        af[i], bf[j], acc[i][j], 0, 0, 0);
            __builtin_amdgcn_s_setprio(0);
        }
    };

    const int NT = K / 64;   // 16
    stage(0, 0);
    stage(1, 1);
    int cur = 0;
    for (int t = 0; t < NT; ++t) {
        if (t + 2 < NT) {
            int nb = cur + 2; if (nb >= 3) nb -= 3;
            stage(nb, t + 2);
            // tile t's 6 loads are the oldest of <=18 outstanding
            asm volatile("s_waitcnt vmcnt(12)" ::: "memory");
        } else if (t + 1 < NT) {
            asm volatile("s_waitcnt vmcnt(6)" ::: "memory");
        } else {
            asm volatile("s_waitcnt vmcnt(0)" ::: "memory");
        }
        __builtin_amdgcn_s_barrier();            // tile t fully in LDS for all waves
        __builtin_amdgcn_sched_barrier(0);       // no ds_read hoists above barrier
        compute(cur);
        __builtin_amdgcn_sched_barrier(0);       // no ds_read sinks below barrier
        __builtin_amdgcn_s_barrier();            // all waves done reading buf cur
        ++cur; if (cur == 3) cur = 0;
    }

#pragma unroll
    for (int i = 0; i < 4; ++i) {
        const int gm0 = bm + wr + i * 16 + g * 4;
#pragma unroll
        for (int j = 0; j < 4; ++j) {
            const int gn = bn + wc + j * 16 + m15;
            if (omode == 0) {
#pragma unroll
                for (int r = 0; r < 4; ++r)
                    ((float*)C)[(size_t)(gm0 + r) * N + gn] = acc[i][j][r];
            } else if (omode == 1) {
#pragma unroll
                for (int r = 0; r < 4; ++r)
                    ((unsigned short*)C)[(size_t)(gm0 + r) * N + gn] = f2h(acc[i][j][r]);
            } else {
                const int b_ = gm0 >> 11, s_ = gm0 & 2047;
                const int h_ = gn >> 6,  d_ = gn & 63;
                us4 o = { f2h(acc[i][j][0]), f2h(acc[i][j][1]),
                          f2h(acc[i][j][2]), f2h(acc[i][j][3]) };
                // [b][h][s>>3][d][s&7]; s_&7 in {0,4} so the us4 is 8B-aligned
                *(us4*)((unsigned short*)C +
                        (((size_t)(b_ * NHEADS + h_) * 256 + (s_ >> 3)) * 64 + d_) * 8
                        + (s_ & 7)) = o;
            }
        }
    }
}

// XCD-panel decode: flat f in [0,256); XCD slot = f&7 (round-robin dispatch),
// each XCD owns 4 consecutive M-panels; all 8 N-tiles of a panel stay on it.
__device__ __forceinline__ void panel_decode(int f, int& bm, int& bn) {
    const int x = f & 7;
    const int k = f >> 3;                 // 0..31
    const int panel = x * 4 + (k >> 3);   // 32 M-panels of 256 rows
    const int ny = k & 7;                 // 8 N-tiles of 128 cols
    bm = panel * 256;
    bn = ny * 128;
}

// Fused Q/K/V projections in one dispatch: blockIdx.z selects the GEMM.
__global__ __launch_bounds__(512)
void proj3_kernel(const unsigned short* __restrict__ qb,
                  const unsigned short* __restrict__ kb,
                  const unsigned short* __restrict__ vb,
                  const unsigned short* __restrict__ wq,
                  const unsigned short* __restrict__ wk,
                  const unsigned short* __restrict__ wv,
                  unsigned short* __restrict__ qproj,
                  unsigned short* __restrict__ kproj,
                  unsigned short* __restrict__ vtw)
{
    __shared__ unsigned short As[3 * 256 * 64];   // 96 KB
    __shared__ unsigned short Bs[3 * 128 * 64];   // 48 KB
    const int z = blockIdx.z;
    const unsigned short* A = (z == 0) ? qb : (z == 1) ? kb : vb;
    const unsigned short* B = (z == 0) ? wq : (z == 1) ? wk : wv;
    void* C = (z == 0) ? (void*)qproj : (z == 1) ? (void*)kproj : (void*)vtw;
    int bm, bn;
    panel_decode(blockIdx.x, bm, bn);
    gemm_body8(A, B, C, D_MODEL, D_MODEL, (z == 2) ? 2 : 1, bm, bn, As, Bs);
}

__global__ __launch_bounds__(512)
void gemm_out_kernel(const unsigned short* __restrict__ A,
                     const unsigned short* __restrict__ B,
                     float* __restrict__ C)
{
    __shared__ unsigned short As[3 * 256 * 64];
    __shared__ unsigned short Bs[3 * 128 * 64];
    int bm, bn;
    panel_decode(blockIdx.x, bm, bn);
    gemm_body8(A, B, C, D_MODEL, D_MODEL, 0, bm, bn, As, Bs);
}

// ---------------------------------------------------------------------------
// Flash attention, transposed-score form, 64 q/wave (mi=4), 2-phase pipeline.
// Flat grid 512 = XCD-grouped: the 8 q-blocks sharing one (b,h)'s K/V run on
// the same XCD (L2 reuse). 256 thr = 4 waves; wave w owns 64 q-rows.
// K-tile = 64 keys, double-buffered (prefetch before compute, one barrier).
// S^T = K·Q^T (k32 MFMA, log2-domain pre-scale); register online softmax
// with DEFER-MAX (T13): cross-lane max shuffles + accO rescale skipped while
// local max <= mrun+8 (P bounded by 2^8, f16/f32 headroom fine).
// P^T round-trips per-mi through a chunk-XOR swizzled 16-row per-wave LDS
// buffer (stride 64, phys chunk = logical ^ (row&7)): write banks even
// 4/bank-pair, read = b128 floor -- the pad-72 layout's 2.1M conflict
// cycles (measured via R5 ablation) are gone. PV + denominator = k32 MFMA.
// qp,kp: [B,S,D_MODEL] f16; vt: [B,H,S/8,DK,8] f16 (granule-interleaved);
// ao: [B,S,D_MODEL] f16
// ---------------------------------------------------------------------------
__global__ __launch_bounds__(256, 2)
void attn_kernel(const unsigned short* __restrict__ qp,
                 const unsigned short* __restrict__ kp,
                 const unsigned short* __restrict__ vt,
                 unsigned short* __restrict__ ao)
{
    __shared__ unsigned short Ks[2][64 * 64];   // [buf][key][d], XOR-swizzled
    __shared__ unsigned short VTs[2][64 * 64];  // [buf][d][key], XOR-swizzled
    __shared__ unsigned short Ps[4][16 * 64];   // per-wave P^T, chunk-XOR swizzled

    const int tid = threadIdx.x;
    const int w = tid >> 6, lane = tid & 63;
    const int g = lane >> 4, m15 = lane & 15;

    // XCD-grouped decode: 64 (b,h) pairs, 8 per XCD; 8 q-tiles per pair.
    const int f = blockIdx.x;
    const int bh = (f & 7) * 8 + ((f >> 3) >> 3);   // 0..63
    const int qt = (f >> 3) & 7;
    const int b = bh >> 4, h = bh & 15;

    const int q0 = qt * 256 + w * 64;
    const size_t rowbase = (size_t)b * SEQ;

    const int srw = lane >> 3;
    const int lc  = (lane & 7) ^ srw;

    // Q fragments (B-operand), pre-scaled by (1/sqrt(dk)) * log2(e)
    const _Float16 qscale = (_Float16)(0.125f * 1.4426950408889634f);
    f16x8 qf[4][2];
#pragma unroll
    for (int mi = 0; mi < 4; ++mi)
#pragma unroll
        for (int t = 0; t < 2; ++t) {
            f16x8 v = *(const f16x8*)(qp + (rowbase + q0 + mi * 16 + m15) * D_MODEL
                                      + h * DK + t * 32 + g * 8);
            qf[mi][t] = v * qscale;
        }

    const _Float16 one16 = (_Float16)1.f;
    const f16x8 onesf = { one16, one16, one16, one16, one16, one16, one16, one16 };

    float mrun[4] = {-INFINITY, -INFINITY, -INFINITY, -INFINITY};
    float lrun[4] = {0.f, 0.f, 0.f, 0.f};

    f32x4 accO[4][4];
#pragma unroll
    for (int mi = 0; mi < 4; ++mi)
#pragma unroll
        for (int i = 0; i < 4; ++i) accO[mi][i] = (f32x4){0.f, 0.f, 0.f, 0.f};

    const unsigned short* kbase = kp + rowbase * D_MODEL + h * DK;
    const unsigned short* vbase = vt + (size_t)(b * NHEADS + h) * DK * SEQ;

    auto stage = [&](int buf, int t) {
#pragma unroll
        for (int it = 0; it < 2; ++it) {
            const int rb = w * 16 + it * 8;
            gld_lds16(kbase + (size_t)(t * 64 + rb + srw) * D_MODEL + lc * 8,
                      &Ks[buf][rb * 64]);
            // vt granule layout: elem = (s8*64 + d)*8 + (s&7); 16B = 8 s for one d
            gld_lds16(vbase + ((size_t)(t * 8 + lc) * 64 + rb + srw) * 8,
                      &VTs[buf][rb * 64]);
        }
    };

    const int NT = SEQ / 64;
    stage(0, 0);
    __syncthreads();   // compiler-emitted vmcnt(0) drains prologue loads

    for (int kt = 0; kt < NT; ++kt) {
        const int cur = kt & 1;
        if (kt + 1 < NT) stage(cur ^ 1, kt + 1);   // prefetch overlaps compute below

        // S^T (log2 domain): ST[km][mi] reg r: key=km*16+g*4+r, q=mi*16+m15
        f32x4 ST[4][4];
        __builtin_amdgcn_s_setprio(1);
#pragma unroll
        for (int km = 0; km < 4; ++km) {
            const int row = km * 16 + m15;
            f16x8 kf0 = *(const f16x8*)&Ks[cur][row * 64 + ((0 + g) ^ (row & 7)) * 8];
            f16x8 kf1 = *(const f16x8*)&Ks[cur][row * 64 + ((4 + g) ^ (row & 7)) * 8];
#pragma unroll
            for (int mi = 0; mi < 4; ++mi) {
                f32x4 z = (f32x4){0.f, 0.f, 0.f, 0.f};
                z = __builtin_amdgcn_mfma_f32_16x16x32_f16(kf0, qf[mi][0], z, 0, 0, 0);
                z = __builtin_amdgcn_mfma_f32_16x16x32_f16(kf1, qf[mi][1], z, 0, 0, 0);
                ST[km][mi] = z;
            }
        }
        __builtin_amdgcn_s_setprio(0);

        // local (per-lane) max trees, v_max3-fusable
        float lmx[4];
#pragma unroll
        for (int mi = 0; mi < 4; ++mi) {
            float t0 = fmaxf(fmaxf(ST[0][mi][0], ST[0][mi][1]), ST[0][mi][2]);
            float t1 = fmaxf(fmaxf(ST[0][mi][3], ST[1][mi][0]), ST[1][mi][1]);
            float t2 = fmaxf(fmaxf(ST[1][mi][2], ST[1][mi][3]), ST[2][mi][0]);
            float t3 = fmaxf(fmaxf(ST[2][mi][1], ST[2][mi][2]), ST[2][mi][3]);
            float t4 = fmaxf(fmaxf(ST[3][mi][0], ST[3][mi][1]), ST[3][mi][2]);
            float u0 = fmaxf(fmaxf(t0, t1), t2);
            float u1 = fmaxf(fmaxf(t3, t4), ST[3][mi][3]);
            lmx[mi] = fmaxf(u0, u1);
        }

        // defer-max: only when some lane's local max exceeds mrun+8 do the
        // cross-lane reduce + running-max update + accO/lrun rescale.
        const float THR = 8.f;
        int need = (lmx[0] > mrun[0] + THR) | (lmx[1] > mrun[1] + THR) |
                   (lmx[2] > mrun[2] + THR) | (lmx[3] > mrun[3] + THR);
        if (__any(need)) {
#pragma unroll
            for (int mi = 0; mi < 4; ++mi) {
                float mx = fmaxf(lmx[mi], __shfl_xor(lmx[mi], 16));
                mx = fmaxf(mx, __shfl_xor(mx, 32));
                float mnew = fmaxf(mrun[mi], mx);
                float scl = fexp2(mrun[mi] - mnew);
                mrun[mi] = mnew;
                lrun[mi] *= scl;
#pragma unroll
                for (int i = 0; i < 4; ++i) accO[mi][i] *= scl;
            }
        }

        // P = 2^(S - mrun) (bounded by 2^THR); chunk-XOR Ps round-trip per-mi
        f16x8 pf[4][2];
#pragma unroll
        for (int mi = 0; mi < 4; ++mi) {
            const float mnew = mrun[mi];
#pragma unroll
            for (int km = 0; km < 4; ++km) {
                float p0 = fexp2(ST[km][mi][0] - mnew);
                float p1 = fexp2(ST[km][mi][1] - mnew);
                float p2 = fexp2(ST[km][mi][2] - mnew);
                float p3 = fexp2(ST[km][mi][3] - mnew);
                h16x2 d0 = __builtin_amdgcn_cvt_pkrtz(p0, p1);
                h16x2 d1 = __builtin_amdgcn_cvt_pkrtz(p2, p3);
                uint2 wv = { __builtin_bit_cast(unsigned, d0),
                             __builtin_bit_cast(unsigned, d1) };
                // logical chunk = km*2 + (g>>1), half = g&1; phys = chunk^(m15&7)
                const int pc = (km * 2 + (g >> 1)) ^ (m15 & 7);
                *(uint2*)&Ps[w][m15 * 64 + pc * 8 + (g & 1) * 4] = wv;
            }
            // read back (in-order per-wave LDS FIFO): logical chunks g and 4+g
            pf[mi][0] = *(const f16x8*)&Ps[w][m15 * 64 + ((0 + g) ^ (m15 & 7)) * 8];
            pf[mi][1] = *(const f16x8*)&Ps[w][m15 * 64 + ((4 + g) ^ (m15 & 7)) * 8];
            // denominator on the matrix pipe: C col=q, all rows = sum_k P^T[k][q]
            f32x4 zs = (f32x4){0.f, 0.f, 0.f, 0.f};
            zs = __builtin_amdgcn_mfma_f32_16x16x32_f16(onesf, pf[mi][0], zs, 0, 0, 0);
            zs = __builtin_amdgcn_mfma_f32_16x16x32_f16(onesf, pf[mi][1], zs, 0, 0, 0);
            lrun[mi] += zs[0];
        }

        // O^T += V^T·P^T (k32)
        __builtin_amdgcn_s_setprio(1);
#pragma unroll
        for (int i = 0; i < 4; ++i) {
            const int row = i * 16 + m15;
            f16x8 vf0 = *(const f16x8*)&VTs[cur][row * 64 + ((0 + g) ^ (row & 7)) * 8];
            f16x8 vf1 = *(const f16x8*)&VTs[cur][row * 64 + ((4 + g) ^ (row & 7)) * 8];
#pragma unroll
            for (int mi = 0; mi < 4; ++mi) {
                f32x4 a = accO[mi][i];
                a = __builtin_amdgcn_mfma_f32_16x16x32_f16(vf0, pf[mi][0], a, 0, 0, 0);
                a = __builtin_amdgcn_mfma_f32_16x16x32_f16(vf1, pf[mi][1], a, 0, 0, 0);
                accO[mi][i] = a;
            }
        }
        __builtin_amdgcn_s_setprio(0);

        __syncthreads();   // drains vmcnt(0) (prefetch done) + protects buffer reuse
    }

    // epilogue: O^T row d=i*16+g*4+r, col q=mi*16+m15 -> ao[b][s][h*64+d]
#pragma unroll
    for (int mi = 0; mi < 4; ++mi) {
        const float li = 1.f / lrun[mi];
        const size_t qg = rowbase + q0 + mi * 16 + m15;
#pragma unroll
        for (int i = 0; i < 4; ++i) {
            us4 o = { f2h(accO[mi][i][0] * li), f2h(accO[mi][i][1] * li),
                      f2h(accO[mi][i][2] * li), f2h(accO[mi][i][3] * li) };
            *(us4*)(ao + qg * D_MODEL + h * DK + i * 16 + g * 4) = o;
        }
    }
}

// ---------------------------------------------------------------------------
extern "C" void kernel_launch(void* const* d_in, const int* in_sizes, int n_in,
                              void* d_out, int out_size, void* d_ws, size_t ws_size,
                              hipStream_t stream)
{
    const float* Q  = (const float*)d_in[0];
    const float* K  = (const float*)d_in[1];
    const float* V  = (const float*)d_in[2];
    const float* Wq = (const float*)d_in[3];
    const float* Wk = (const float*)d_in[4];
    const float* Wv = (const float*)d_in[5];
    const float* Wo = (const float*)d_in[6];

    unsigned short* base = (unsigned short*)d_ws;
    unsigned short* qb = base;
    unsigned short* kb = qb + TENS;
    unsigned short* vb = kb + TENS;
    unsigned short* wq = vb + TENS;
    unsigned short* wk = wq + WELT;
    unsigned short* wv = wk + WELT;
    unsigned short* wo = wv + WELT;
    unsigned short* qproj = wo + WELT;
    unsigned short* kproj = qproj + TENS;
    unsigned short* vtw   = kproj + TENS;    // [B,H,S/8,DK,8] granule-interleaved
    unsigned short* aow   = vtw + TENS;

    convert_kernel<<<dim3(TENS / 1024, 4), 256, 0, stream>>>(Q, K, V, Wq, Wk, Wv, Wo, base);

    proj3_kernel<<<dim3(256, 1, 3), 512, 0, stream>>>(
        qb, kb, vb, wq, wk, wv, qproj, kproj, vtw);

    attn_kernel<<<dim3(512, 1, 1), 256, 0, stream>>>(
        qproj, kproj, vtw, aow);

    gemm_out_kernel<<<dim3(256, 1, 1), 512, 0, stream>>>(
        aow, wo, (float*)d_out);
}